// Round 8
// baseline (137.917 us; speedup 1.0000x reference)
//
#include <hip/hip_runtime.h>

#define BATCH 32768
#define DIM   256
#define NEXP  8
#define MT    64          // rows per tile (B kernel)
#define STRIDE 264        // DIM + 8 bf16 pad (measured 0 bank conflicts)

typedef __bf16 bf16x8 __attribute__((ext_vector_type(8)));
typedef __bf16 bf16x4 __attribute__((ext_vector_type(4)));
typedef float  f32x16 __attribute__((ext_vector_type(16)));

static __device__ __forceinline__ float sigmoid_f(float x) {
    return __builtin_amdgcn_rcpf(1.f + __expf(-x));
}
static __device__ __forceinline__ float tanh_f(float x) {
    return 1.f - 2.f * __builtin_amdgcn_rcpf(__expf(2.f * x) + 1.f);
}

// LDS-only barrier (no vmcnt drain): all cross-thread data flows through LDS;
// global loads are consumed by the issuing thread; out is never read back.
static __device__ __forceinline__ void lds_barrier() {
    asm volatile("s_waitcnt lgkmcnt(0)\n\ts_barrier" ::: "memory");
}

// ---- fused prep (unchanged).
// Blocks 0..255: pack W1/W2 fp32->bf16 into MFMA-B-fragment order.
// Blocks 256..383: scatter sample indices into per-expert regions.
__global__ void prep_kernel(const float* __restrict__ W1, const float* __restrict__ W2,
                            const float* __restrict__ t,
                            bf16x8* __restrict__ W1p, bf16x8* __restrict__ W2p,
                            int* __restrict__ cursor, int* __restrict__ idxb) {
    const int b = blockIdx.x;
    if (b < 256) {
        const int tid = b * 256 + threadIdx.x;   // = e*8192 + col*32 + ks*2 + kh
        const int kh  = tid & 1;
        const int ks  = (tid >> 1) & 15;
        const int col = (tid >> 5) & 255;
        const int e   = tid >> 13;
        const long src = (long)tid * 8;          // consecutive floats -> coalesced
        const float4 a0 = *(const float4*)(W1 + src);
        const float4 a1 = *(const float4*)(W1 + src + 4);
        const float4 c0 = *(const float4*)(W2 + src);
        const float4 c1 = *(const float4*)(W2 + src + 4);
        bf16x8 w1, w2;
        w1[0] = (__bf16)a0.x; w1[1] = (__bf16)a0.y; w1[2] = (__bf16)a0.z; w1[3] = (__bf16)a0.w;
        w1[4] = (__bf16)a1.x; w1[5] = (__bf16)a1.y; w1[6] = (__bf16)a1.z; w1[7] = (__bf16)a1.w;
        w2[0] = (__bf16)c0.x; w2[1] = (__bf16)c0.y; w2[2] = (__bf16)c0.z; w2[3] = (__bf16)c0.w;
        w2[4] = (__bf16)c1.x; w2[5] = (__bf16)c1.y; w2[6] = (__bf16)c1.z; w2[7] = (__bf16)c1.w;
        const int dst = (e << 13) | ((col >> 5) << 10) | (ks << 6) | (kh << 5) | (col & 31);
        W1p[dst] = w1;
        W2p[dst] = w2;
    } else {
        __shared__ int h[NEXP], base[NEXP];
        if (threadIdx.x < NEXP) h[threadIdx.x] = 0;
        __syncthreads();
        const int i = (b - 256) * 256 + threadIdx.x;
        const int e = min((int)(t[i] * 8.0f), NEXP - 1);
        const int lr = atomicAdd(&h[e], 1);
        __syncthreads();
        if (threadIdx.x < NEXP)
            base[threadIdx.x] = atomicAdd(&cursor[threadIdx.x], h[threadIdx.x]);
        __syncthreads();
        idxb[e * BATCH + base[e] + lr] = i;
    }
}

// ---- gather-pack: 8192 independent waves, one padded row each per pass.
// Reads y[idx] (1 KB coalesced) -> writes packed bf16 yp[e][q] (512 B
// coalesced). No barriers, no reuse, max TLP: the "fill-shaped" kernel
// that the R0-R7 counters say this chip runs at 6+ TB/s. Rows padded to
// 64-row tiles (clamped repeat of last row) so mlp staging is branchless.
__global__ void __launch_bounds__(256, 8)
gather_kernel(const float* __restrict__ y, const int* __restrict__ cnt,
              const int* __restrict__ idxb, __bf16* __restrict__ yp) {
    const int wave = threadIdx.x >> 6;
    const int lane = threadIdx.x & 63;
    const int wid  = blockIdx.x * 4 + wave;
    const int totw = gridDim.x * 4;
#pragma unroll
    for (int e = 0; e < NEXP; ++e) {
        const int ce = cnt[e];
        const int Re = ((ce + 63) >> 6) << 6;   // padded to 64-row tiles
        const int* idx_e = idxb + e * BATCH;
        __bf16* yp_e = yp + (long)e * BATCH * DIM;
        for (int q = wid; q < Re; q += totw) {
            const int g = idx_e[min(q, ce - 1)];            // wave-uniform
            const float4 v = *(const float4*)(y + (long)g * DIM + lane * 4);
            bf16x4 wv;
            wv[0] = (__bf16)v.x; wv[1] = (__bf16)v.y;
            wv[2] = (__bf16)v.z; wv[3] = (__bf16)v.w;
            *(bf16x4*)(yp_e + (long)q * DIM + lane * 4) = wv;
        }
    }
}

// ---- grouped fused 2-layer MLP, expert-pinned blocks, weights in registers,
// SEQUENTIAL staging. 256 blocks (1/CU) x 512 threads (8 waves x 32 cols,
// acc[2] = 64 rows). Tiles now read from packed bf16 yp: staging is a
// contiguous 32 KB read with NO index dependency -> next tile prefetches
// into 16 VGPRs under ~3k cy of G1+tanh+G2 cover, and lds_barrier never
// drains it. This removes the per-tile idx->row HBM chain that R3/R5/R6/R7
// A/B results isolated as the residual cost.
__global__ void __launch_bounds__(512, 2)
mlp_kernel(const __bf16* __restrict__ yp,
           const float* __restrict__ scales,
           const float* __restrict__ shifta,
           const float* __restrict__ shiftb,
           const float* __restrict__ b1,
           const float* __restrict__ b2,
           const bf16x8* __restrict__ W1p,
           const bf16x8* __restrict__ W2p,
           const int* __restrict__ cnt,
           const int* __restrict__ idxb,
           float* __restrict__ out) {
    __shared__ __bf16 ab[MT * STRIDE];   // y tile (bf16), then tanh(h); 33.8 KB
    __shared__ int rows[MT];

    const int tx   = threadIdx.x;
    const int wave = tx >> 6;     // 0..7
    const int lane = tx & 63;
    const int nl   = lane & 31;
    const int kh   = lane >> 5;
    const int n    = wave * 32 + nl;   // this thread's output column (fixed)

    const int e    = blockIdx.x >> 5;   // expert pinned to block
    const int slot = blockIdx.x & 31;
    const int ce   = cnt[e];
    const int nt   = (ce + MT - 1) >> 6;   // 64-row tiles
    if (slot >= nt) return;                // block-uniform
    const int* idx_e = idxb + e * BATCH;
    const __bf16* yp_e = yp + (long)e * BATCH * DIM;

    // ---- both GEMMs' B-fragments in registers (128 VGPR, loaded once)
    const bf16x8* w1p = W1p + (e << 13) + (wave << 10) + lane;
    const bf16x8* w2p = W2p + (e << 13) + (wave << 10) + lane;
    bf16x8 wA[16], wB[16];
#pragma unroll
    for (int ks = 0; ks < 16; ++ks) {
        wA[ks] = w1p[ks << 6];
        wB[ks] = w2p[ks << 6];
    }

    // ---- hoisted epilogue constants
    const float sa = sigmoid_f(shifta[0]);
    const float sb = sigmoid_f(shiftb[0]);
    const float k1 = 0.5f * (sb + sa);           // 0.5*(b-a), a=-sa, b=sb
    const float k2 = 0.5f * (sb - sa);           // 0.5*(a+b)
    const bool needy = (k2 != 0.0f);             // exactly 0 with given inputs
    const float c1  = k1 * sigmoid_f(scales[n]);
    const float b1v = b1[(e << 8) | n];
    const float b2v = b2[(e << 8) | n];

    // ---- prologue: stage tile `slot` (sequential 32 KB from yp)
    int ti = slot;
    {
        const int rbase = ti * MT;
        if (wave == 0) rows[lane] = (lane < ce - rbase) ? idx_e[rbase + lane] : -1;
#pragma unroll
        for (int p = 0; p < 8; ++p) {
            const int r = p * 8 + wave;
            bf16x4 v = *(const bf16x4*)(yp_e + (long)(rbase + r) * DIM + lane * 4);
            *(bf16x4*)(ab + r * STRIDE + lane * 4) = v;
        }
    }
    lds_barrier();

    for (;;) {
        // ---- prefetch next tile into regs: address-only, no idx chain
        const int ti2 = ti + 32;
        const bool have_next = (ti2 < nt);
        bf16x4 v2[8];
        int row2 = -1;
        if (have_next) {
            const int rbase2 = ti2 * MT;
#pragma unroll
            for (int p = 0; p < 8; ++p)
                v2[p] = *(const bf16x4*)(yp_e + (long)(rbase2 + p * 8 + wave) * DIM + lane * 4);
            if (wave == 0 && lane < ce - rbase2) row2 = idx_e[rbase2 + lane];
        }

        const __bf16* apt0 = ab + nl * STRIDE + kh * 8;          // rows 0..31
        const __bf16* apt1 = ab + (32 + nl) * STRIDE + kh * 8;   // rows 32..63

        // ---- GEMM1: h = y @ W1[e]^T   (pure LDS + reg-resident B)
        f32x16 acc[2] = {};
#pragma unroll
        for (int ks = 0; ks < 16; ++ks) {
            bf16x8 a0 = *(const bf16x8*)(apt0 + ks * 16);
            bf16x8 a1 = *(const bf16x8*)(apt1 + ks * 16);
            acc[0] = __builtin_amdgcn_mfma_f32_32x32x16_bf16(a0, wA[ks], acc[0], 0, 0, 0);
            acc[1] = __builtin_amdgcn_mfma_f32_32x32x16_bf16(a1, wA[ks], acc[1], 0, 0, 0);
        }
        lds_barrier();     // GEMM1 ds-reads done (prefetch stays in flight)

        // ---- tanh(h + b1) -> ab (C/D: col=nl, row=mi*32+(r&3)+8*(r>>2)+4*kh)
#pragma unroll
        for (int mi = 0; mi < 2; ++mi)
#pragma unroll
            for (int r = 0; r < 16; ++r) {
                const int row = mi * 32 + (r & 3) + ((r >> 2) << 3) + (kh << 2);
                ab[row * STRIDE + n] = (__bf16)tanh_f(acc[mi][r] + b1v);
            }
        lds_barrier();

        // ---- GEMM2: f = h @ W2[e]^T
        f32x16 acc2[2] = {};
#pragma unroll
        for (int ks = 0; ks < 16; ++ks) {
            bf16x8 a0 = *(const bf16x8*)(apt0 + ks * 16);
            bf16x8 a1 = *(const bf16x8*)(apt1 + ks * 16);
            acc2[0] = __builtin_amdgcn_mfma_f32_32x32x16_bf16(a0, wB[ks], acc2[0], 0, 0, 0);
            acc2[1] = __builtin_amdgcn_mfma_f32_32x32x16_bf16(a1, wB[ks], acc2[1], 0, 0, 0);
        }

        // ---- epilogue: out = k1*sig(scales)*(f+b2) + k2*y
#pragma unroll
        for (int mi = 0; mi < 2; ++mi)
#pragma unroll
            for (int r = 0; r < 16; ++r) {
                const int row = mi * 32 + (r & 3) + ((r >> 2) << 3) + (kh << 2);
                const int g = rows[row];
                if (g >= 0) {
                    float res = c1 * (acc2[mi][r] + b2v);
                    if (needy) res += k2 * (float)yp_e[(long)(ti * MT + row) * DIM + n];
                    out[(long)g * DIM + n] = res;
                }
            }

        if (!have_next) return;   // block-uniform

        lds_barrier();     // GEMM2 ds-reads + rows[] reads done

        // ---- write-late: prefetched regs -> LDS (precise vmcnt wait here)
        if (wave == 0) rows[lane] = row2;
#pragma unroll
        for (int p = 0; p < 8; ++p)
            *(bf16x4*)(ab + (p * 8 + wave) * STRIDE + lane * 4) = v2[p];
        lds_barrier();

        ti = ti2;
    }
}

extern "C" void kernel_launch(void* const* d_in, const int* in_sizes, int n_in,
                              void* d_out, int out_size, void* d_ws, size_t ws_size,
                              hipStream_t stream) {
    const float* t      = (const float*)d_in[0];
    const float* y      = (const float*)d_in[1];
    const float* W1     = (const float*)d_in[2];
    const float* b1     = (const float*)d_in[3];
    const float* W2     = (const float*)d_in[4];
    const float* b2     = (const float*)d_in[5];
    const float* scales = (const float*)d_in[6];
    const float* shifta = (const float*)d_in[7];
    const float* shiftb = (const float*)d_in[8];
    float* out = (float*)d_out;

    char* ws = (char*)d_ws;
    int* cursor = (int*)ws;                               // [8]
    int* idxb   = (int*)(ws + 256);                       // [8][32768]
    bf16x8* W1p = (bf16x8*)(ws + 256 + NEXP * BATCH * 4); // packed 1MB
    bf16x8* W2p = W1p + 65536;
    __bf16* yp  = (__bf16*)(ws + 256 + NEXP * BATCH * 4 + 2 * 1048576); // 128MB

    hipMemsetAsync(cursor, 0, 32, stream);
    prep_kernel<<<384, 256, 0, stream>>>(W1, W2, t, W1p, W2p, cursor, idxb);
    gather_kernel<<<2048, 256, 0, stream>>>(y, cursor, idxb, yp);
    // 256 expert-pinned blocks (32 per expert), 1 block/CU, 2-3 tiles each
    mlp_kernel<<<256, 512, 0, stream>>>(yp, scales, shifta, shiftb, b1, b2,
                                        W1p, W2p, cursor, idxb, out);
}

// Round 9
// 122.579 us; speedup vs baseline: 1.1251x; 1.1251x over previous
//
#include <hip/hip_runtime.h>

#define BATCH 32768
#define DIM   256
#define NEXP  8
#define MT    32          // rows per tile
#define STRIDE 264        // DIM + 8 bf16 pad (measured 0 bank conflicts)
#define FCAP  5120        // per-expert flat-list capacity (ce ~ 4096 +/- 60)

typedef __bf16 bf16x8 __attribute__((ext_vector_type(8)));
typedef __bf16 bf16x4 __attribute__((ext_vector_type(4)));
typedef float  f32x16 __attribute__((ext_vector_type(16)));

static __device__ __forceinline__ float sigmoid_f(float x) {
    return __builtin_amdgcn_rcpf(1.f + __expf(-x));
}
static __device__ __forceinline__ float tanh_f(float x) {
    return 1.f - 2.f * __builtin_amdgcn_rcpf(__expf(2.f * x) + 1.f);
}

// LDS-only barrier (no vmcnt drain): all cross-thread data flows through LDS;
// global loads are consumed by the issuing thread; out is never read back.
static __device__ __forceinline__ void lds_barrier() {
    asm volatile("s_waitcnt lgkmcnt(0)\n\ts_barrier" ::: "memory");
}

// ---- prep. Blocks 0..255: pack W1/W2 fp32->bf16 into MFMA-B-fragment order
// (unchanged). Blocks 256..383: ATOMIC-FREE scatter — block s writes its
// samples for expert e into private segment idxb[e][s][0..255] and counts to
// cnts[e][s]. No global cursor => no hipMemsetAsync dispatch (R8 isolated
// ~4-7us per-dispatch overhead; this removes one of three dispatches).
__global__ void prep_kernel(const float* __restrict__ W1, const float* __restrict__ W2,
                            const float* __restrict__ t,
                            bf16x8* __restrict__ W1p, bf16x8* __restrict__ W2p,
                            int* __restrict__ cnts, int* __restrict__ idxb) {
    const int b = blockIdx.x;
    if (b < 256) {
        const int tid = b * 256 + threadIdx.x;   // = e*8192 + col*32 + ks*2 + kh
        const int kh  = tid & 1;
        const int ks  = (tid >> 1) & 15;
        const int col = (tid >> 5) & 255;
        const int e   = tid >> 13;
        const long src = (long)tid * 8;          // consecutive floats -> coalesced
        const float4 a0 = *(const float4*)(W1 + src);
        const float4 a1 = *(const float4*)(W1 + src + 4);
        const float4 c0 = *(const float4*)(W2 + src);
        const float4 c1 = *(const float4*)(W2 + src + 4);
        bf16x8 w1, w2;
        w1[0] = (__bf16)a0.x; w1[1] = (__bf16)a0.y; w1[2] = (__bf16)a0.z; w1[3] = (__bf16)a0.w;
        w1[4] = (__bf16)a1.x; w1[5] = (__bf16)a1.y; w1[6] = (__bf16)a1.z; w1[7] = (__bf16)a1.w;
        w2[0] = (__bf16)c0.x; w2[1] = (__bf16)c0.y; w2[2] = (__bf16)c0.z; w2[3] = (__bf16)c0.w;
        w2[4] = (__bf16)c1.x; w2[5] = (__bf16)c1.y; w2[6] = (__bf16)c1.z; w2[7] = (__bf16)c1.w;
        const int dst = (e << 13) | ((col >> 5) << 10) | (ks << 6) | (kh << 5) | (col & 31);
        W1p[dst] = w1;
        W2p[dst] = w2;
    } else {
        __shared__ int h[NEXP];
        const int sbid = b - 256;                // 0..127
        if (threadIdx.x < NEXP) h[threadIdx.x] = 0;
        __syncthreads();
        const int i = sbid * 256 + threadIdx.x;
        const int e = min((int)(t[i] * 8.0f), NEXP - 1);
        const int lr = atomicAdd(&h[e], 1);      // LDS atomic only
        idxb[(e << 15) | (sbid << 8) | lr] = i;  // e*32768 + sbid*256 + lr
        __syncthreads();
        if (threadIdx.x < NEXP)
            cnts[(threadIdx.x << 7) | sbid] = h[threadIdx.x];
    }
}

// ---- producer-consumer wave-specialized MLP (R7 core, measured best) with
// LDS flat index list. 256 blocks (1/CU) x 512 threads. Prologue: build the
// dense per-expert sample list flat[0..ce) from the 128 ragged segments
// (prefix over cnts, parallel copy) — indices then come from LDS, removing
// the idx L2 hop from the stage chain and the rowsb bookkeeping.
// Waves 0-3 (G1): W1 frags in 128 VGPR, GEMM1+tanh -> H. Waves 4-7 (G2):
// W2 frags, GEMM2+epilogue from H, and stage next y-tile (issue-early /
// write-late). Y and H double-buffered; ONE lds_barrier per region.
__global__ void __launch_bounds__(512, 2)
mlp_kernel(const float* __restrict__ y,
           const float* __restrict__ scales,
           const float* __restrict__ shifta,
           const float* __restrict__ shiftb,
           const float* __restrict__ b1,
           const float* __restrict__ b2,
           const bf16x8* __restrict__ W1p,
           const bf16x8* __restrict__ W2p,
           const int* __restrict__ cnts,
           const int* __restrict__ idxb,
           float* __restrict__ out) {
    __shared__ __bf16 Y[2][MT * STRIDE];   // staged y tiles (bf16)   33.8 KB
    __shared__ __bf16 H[2][MT * STRIDE];   // tanh(h) tiles           33.8 KB
    __shared__ int seg[128];               // per-segment counts
    __shared__ int flat[FCAP];             // dense sample indices    20 KB

    const int tx   = threadIdx.x;
    const int wave = tx >> 6;     // 0..7
    const int lane = tx & 63;
    const int nl   = lane & 31;
    const int kh   = lane >> 5;
    const bool isG1 = (wave < 4);
    const int  w    = wave & 3;        // slice-group 0..3 within role
    const int  n0   = w * 64 + nl;     // output col, slice 0
    const int  n1   = n0 + 32;         // output col, slice 1

    const int e    = blockIdx.x >> 5;   // expert pinned to block
    const int slot = blockIdx.x & 31;

    // ---- prologue 1: segment counts -> LDS
    if (tx < 128) seg[tx] = cnts[(e << 7) | tx];
    lds_barrier();

    // ---- prefix scan (every thread computes ce; tx<128 also its copy base)
    int ce = 0, base = 0;
#pragma unroll 8
    for (int j = 0; j < 128; ++j) {
        if (j == tx) base = ce;
        ce += seg[j];
    }
    ce = min(ce, FCAP);

    const int nt_e = (ce + MT - 1) >> 5;          // global 32-row tiles
    if (slot >= nt_e) return;                     // block-uniform
    const int nt = ((nt_e - slot) + 31) >> 5;     // tiles for this block

    // ---- role-specific weights: 32 frags = 128 VGPR (W1 for G1, W2 for G2)
    const bf16x8* wp = (isG1 ? W1p : W2p) + (e << 13) + ((w * 2) << 10) + lane;
    bf16x8 wf[2][16];
#pragma unroll
    for (int s = 0; s < 2; ++s)
#pragma unroll
        for (int ks = 0; ks < 16; ++ks)
            wf[s][ks] = wp[(s << 10) + (ks << 6)];

    // ---- prologue 2: copy ragged segments -> dense flat list
    if (tx < 128) {
        const int c = seg[tx];
        const int* src = idxb + (e << 15) + (tx << 8);
        for (int j = 0; j < c; ++j) {
            const int d = base + j;
            if (d < FCAP) flat[d] = src[j];
        }
    }

    // ---- hoisted constants
    const float sa = sigmoid_f(shifta[0]);
    const float sb = sigmoid_f(shiftb[0]);
    const float k1 = 0.5f * (sb + sa);           // 0.5*(b-a), a=-sa, b=sb
    const float k2 = 0.5f * (sb - sa);           // 0.5*(a+b)
    const bool needy = (k2 != 0.0f);             // exactly 0 with given inputs
    float b1v[2], b2v[2], cc[2];
    b1v[0] = b1[(e << 8) | n0]; b1v[1] = b1[(e << 8) | n1];
    b2v[0] = b2[(e << 8) | n0]; b2v[1] = b2[(e << 8) | n1];
    cc[0]  = k1 * sigmoid_f(scales[n0]); cc[1] = k1 * sigmoid_f(scales[n1]);

    lds_barrier();   // flat[] complete

    // ---- prologue 3: G2-waves stage tile 0 into Y[0]
    if (!isG1) {
        const int rbase = slot * MT;
#pragma unroll
        for (int p = 0; p < 8; ++p) {
            const int r = w * 8 + p;
            const int g = flat[min(rbase + r, ce - 1)];
            const float4 v = *(const float4*)(y + (long)g * DIM + lane * 4);
            bf16x4 wv;
            wv[0] = (__bf16)v.x; wv[1] = (__bf16)v.y; wv[2] = (__bf16)v.z; wv[3] = (__bf16)v.w;
            *(bf16x4*)(&Y[0][r * STRIDE + lane * 4]) = wv;
        }
    }
    lds_barrier();

    // ---- region t: G1 computes tile t (if t<nt); G2 computes tile t-1
    // (if t>=1) and stages tile t+1 (if t+1<nt). Buffers disjoint by parity.
    for (int t = 0; t <= nt; ++t) {
        if (isG1) {
            if (t < nt) {
                const __bf16* ap = &Y[t & 1][nl * STRIDE + kh * 8];
                f32x16 a0v = {}, a1v = {};
#pragma unroll
                for (int ks = 0; ks < 16; ++ks) {
                    bf16x8 a = *(const bf16x8*)(ap + ks * 16);   // 1 read, 2 MFMA
                    a0v = __builtin_amdgcn_mfma_f32_32x32x16_bf16(a, wf[0][ks], a0v, 0, 0, 0);
                    a1v = __builtin_amdgcn_mfma_f32_32x32x16_bf16(a, wf[1][ks], a1v, 0, 0, 0);
                }
                __bf16* hb = &H[t & 1][0];
#pragma unroll
                for (int r = 0; r < 16; ++r) {
                    const int row = (r & 3) + ((r >> 2) << 3) + (kh << 2);
                    hb[row * STRIDE + n0] = (__bf16)tanh_f(a0v[r] + b1v[0]);
                    hb[row * STRIDE + n1] = (__bf16)tanh_f(a1v[r] + b1v[1]);
                }
            }
        } else {
            const bool do_stage = (t + 1 < nt);
            float4 vs[8];
            if (do_stage) {   // issue-early: idx from LDS, loads ride under GEMM2
                const int rbase = (slot + (t + 1) * 32) * MT;
#pragma unroll
                for (int p = 0; p < 8; ++p) {
                    const int g = flat[min(rbase + w * 8 + p, ce - 1)];
                    vs[p] = *(const float4*)(y + (long)g * DIM + lane * 4);
                }
            }
            if (t >= 1) {
                const __bf16* ap = &H[(t - 1) & 1][nl * STRIDE + kh * 8];
                f32x16 a0v = {}, a1v = {};
#pragma unroll
                for (int ks = 0; ks < 16; ++ks) {
                    bf16x8 a = *(const bf16x8*)(ap + ks * 16);
                    a0v = __builtin_amdgcn_mfma_f32_32x32x16_bf16(a, wf[0][ks], a0v, 0, 0, 0);
                    a1v = __builtin_amdgcn_mfma_f32_32x32x16_bf16(a, wf[1][ks], a1v, 0, 0, 0);
                }
                const int rbase = (slot + (t - 1) * 32) * MT;
#pragma unroll
                for (int r = 0; r < 16; ++r) {
                    const int row = (r & 3) + ((r >> 2) << 3) + (kh << 2);
                    const int q = rbase + row;
                    if (q < ce) {
                        const int g = flat[q];
                        float r0 = cc[0] * (a0v[r] + b2v[0]);
                        float r1 = cc[1] * (a1v[r] + b2v[1]);
                        if (needy) {
                            r0 += k2 * y[(long)g * DIM + n0];
                            r1 += k2 * y[(long)g * DIM + n1];
                        }
                        out[(long)g * DIM + n0] = r0;
                        out[(long)g * DIM + n1] = r1;
                    }
                }
            }
            if (do_stage) {   // write-late: precise vmcnt wait for vs here
                const int kb = t + 1;
#pragma unroll
                for (int p = 0; p < 8; ++p) {
                    const int r = w * 8 + p;
                    const float4 v = vs[p];
                    bf16x4 wv;
                    wv[0] = (__bf16)v.x; wv[1] = (__bf16)v.y; wv[2] = (__bf16)v.z; wv[3] = (__bf16)v.w;
                    *(bf16x4*)(&Y[kb & 1][r * STRIDE + lane * 4]) = wv;
                }
            }
        }
        lds_barrier();
    }
}

extern "C" void kernel_launch(void* const* d_in, const int* in_sizes, int n_in,
                              void* d_out, int out_size, void* d_ws, size_t ws_size,
                              hipStream_t stream) {
    const float* t      = (const float*)d_in[0];
    const float* y      = (const float*)d_in[1];
    const float* W1     = (const float*)d_in[2];
    const float* b1     = (const float*)d_in[3];
    const float* W2     = (const float*)d_in[4];
    const float* b2     = (const float*)d_in[5];
    const float* scales = (const float*)d_in[6];
    const float* shifta = (const float*)d_in[7];
    const float* shiftb = (const float*)d_in[8];
    float* out = (float*)d_out;

    char* ws = (char*)d_ws;
    int* cnts   = (int*)ws;                                // [8][128]  4 KB
    int* idxb   = (int*)(ws + 4096);                       // [8][128][256] 1 MB
    bf16x8* W1p = (bf16x8*)(ws + 4096 + NEXP * BATCH * 4); // packed 1 MB
    bf16x8* W2p = W1p + 65536;

    // two dispatches total (no memset, no gather)
    prep_kernel<<<384, 256, 0, stream>>>(W1, W2, t, W1p, W2p, cnts, idxb);
    mlp_kernel<<<256, 512, 0, stream>>>(y, scales, shifta, shiftb, b1, b2,
                                        W1p, W2p, cnts, idxb, out);
}

// Round 10
// 120.448 us; speedup vs baseline: 1.1450x; 1.0177x over previous
//
#include <hip/hip_runtime.h>

#define BATCH 32768
#define DIM   256
#define NEXP  8
#define MT    32          // rows per tile
#define STRIDE 264        // DIM + 8 bf16 pad (measured 0 bank conflicts)

typedef __bf16 bf16x8 __attribute__((ext_vector_type(8)));
typedef __bf16 bf16x4 __attribute__((ext_vector_type(4)));
typedef float  f32x16 __attribute__((ext_vector_type(16)));

static __device__ __forceinline__ float sigmoid_f(float x) {
    return __builtin_amdgcn_rcpf(1.f + __expf(-x));
}
static __device__ __forceinline__ float tanh_f(float x) {
    return 1.f - 2.f * __builtin_amdgcn_rcpf(__expf(2.f * x) + 1.f);
}

// LDS-only barrier (no vmcnt drain): all cross-thread data flows through LDS;
// global loads are consumed by the issuing thread; out is never read back.
static __device__ __forceinline__ void lds_barrier() {
    asm volatile("s_waitcnt lgkmcnt(0)\n\ts_barrier" ::: "memory");
}

// ---- fused prep (R7 version: cursor + atomics; R9 showed the atomic-free
// variant is worth exactly 0 and costs LDS + prologue time in mlp).
__global__ void prep_kernel(const float* __restrict__ W1, const float* __restrict__ W2,
                            const float* __restrict__ t,
                            bf16x8* __restrict__ W1p, bf16x8* __restrict__ W2p,
                            int* __restrict__ cursor, int* __restrict__ idxb) {
    const int b = blockIdx.x;
    if (b < 256) {
        const int tid = b * 256 + threadIdx.x;   // = e*8192 + col*32 + ks*2 + kh
        const int kh  = tid & 1;
        const int ks  = (tid >> 1) & 15;
        const int col = (tid >> 5) & 255;
        const int e   = tid >> 13;
        const long src = (long)tid * 8;          // consecutive floats -> coalesced
        const float4 a0 = *(const float4*)(W1 + src);
        const float4 a1 = *(const float4*)(W1 + src + 4);
        const float4 c0 = *(const float4*)(W2 + src);
        const float4 c1 = *(const float4*)(W2 + src + 4);
        bf16x8 w1, w2;
        w1[0] = (__bf16)a0.x; w1[1] = (__bf16)a0.y; w1[2] = (__bf16)a0.z; w1[3] = (__bf16)a0.w;
        w1[4] = (__bf16)a1.x; w1[5] = (__bf16)a1.y; w1[6] = (__bf16)a1.z; w1[7] = (__bf16)a1.w;
        w2[0] = (__bf16)c0.x; w2[1] = (__bf16)c0.y; w2[2] = (__bf16)c0.z; w2[3] = (__bf16)c0.w;
        w2[4] = (__bf16)c1.x; w2[5] = (__bf16)c1.y; w2[6] = (__bf16)c1.z; w2[7] = (__bf16)c1.w;
        const int dst = (e << 13) | ((col >> 5) << 10) | (ks << 6) | (kh << 5) | (col & 31);
        W1p[dst] = w1;
        W2p[dst] = w2;
    } else {
        __shared__ int h[NEXP], base[NEXP];
        if (threadIdx.x < NEXP) h[threadIdx.x] = 0;
        __syncthreads();
        const int i = (b - 256) * 256 + threadIdx.x;
        const int e = min((int)(t[i] * 8.0f), NEXP - 1);
        const int lr = atomicAdd(&h[e], 1);
        __syncthreads();
        if (threadIdx.x < NEXP)
            base[threadIdx.x] = atomicAdd(&cursor[threadIdx.x], h[threadIdx.x]);
        __syncthreads();
        idxb[e * BATCH + base[e] + lr] = i;
    }
}

// ---- producer-consumer wave-specialized MLP (R7 core, measured best) +
// three overlap fixes isolated by the R8/R9 accounting:
//  (1) idx-prefetch ring: G2 loads tile t+2's INDICES while staging tile
//      t+1's DATA — the idx->y two-hop chain never appears in one region.
//  (2) prologue role overlap: G1 stages tile 0 (HBM) while G2 loads its
//      weight fragments (L2) — serial prologue halved.
//  (3) T5 s_setprio(1) around MFMA clusters — the G1/G2 role split gives
//      the SIMD scheduler something to arbitrate (catalog prerequisite met).
__global__ void __launch_bounds__(512, 2)
mlp_kernel(const float* __restrict__ y,
           const float* __restrict__ scales,
           const float* __restrict__ shifta,
           const float* __restrict__ shiftb,
           const float* __restrict__ b1,
           const float* __restrict__ b2,
           const bf16x8* __restrict__ W1p,
           const bf16x8* __restrict__ W2p,
           const int* __restrict__ cnt,
           const int* __restrict__ idxb,
           float* __restrict__ out) {
    __shared__ __bf16 Y[2][MT * STRIDE];   // staged y tiles (bf16)   33.8 KB
    __shared__ __bf16 H[2][MT * STRIDE];   // tanh(h) tiles           33.8 KB
    __shared__ int rowsb[4][MT];           // gathered row indices, 4-deep ring

    const int tx   = threadIdx.x;
    const int wave = tx >> 6;     // 0..7
    const int lane = tx & 63;
    const int nl   = lane & 31;
    const int kh   = lane >> 5;
    const bool isG1 = (wave < 4);
    const int  w    = wave & 3;        // slice-group 0..3 within role
    const int  n0   = w * 64 + nl;     // output col, slice 0
    const int  n1   = n0 + 32;         // output col, slice 1

    const int e    = blockIdx.x >> 5;   // expert pinned to block
    const int slot = blockIdx.x & 31;
    const int ce   = cnt[e];
    const int nt_e = (ce + MT - 1) >> 5;
    if (slot >= nt_e) return;           // block-uniform
    const int nt   = ((nt_e - slot) + 31) >> 5;   // tiles for this block
    const int* idx_e = idxb + e * BATCH;

    const bf16x8* wp = (isG1 ? W1p : W2p) + (e << 13) + ((w * 2) << 10) + lane;
    bf16x8 wf[2][16];
    int gcur[8];

    // ---- prologue, role-overlapped:
    // G1: gather+stage tile 0 (HBM latency), weights issued behind it.
    // G2: weight frags (L2) + tile-1 index prefetch.
    if (isG1) {
        const int rbase = slot * MT;
        int g0[8];
#pragma unroll
        for (int p = 0; p < 8; ++p)
            g0[p] = idx_e[min(rbase + w * 8 + p, ce - 1)];
        float4 v0[8];
#pragma unroll
        for (int p = 0; p < 8; ++p)
            v0[p] = *(const float4*)(y + (long)g0[p] * DIM + lane * 4);
#pragma unroll
        for (int s = 0; s < 2; ++s)
#pragma unroll
            for (int ks = 0; ks < 16; ++ks)
                wf[s][ks] = wp[(s << 10) + (ks << 6)];
#pragma unroll
        for (int p = 0; p < 8; ++p) {
            const int r = w * 8 + p;
            if (lane == 0) rowsb[0][r] = (rbase + r < ce) ? g0[p] : -1;
            const float4 v = v0[p];
            bf16x4 wv;
            wv[0] = (__bf16)v.x; wv[1] = (__bf16)v.y; wv[2] = (__bf16)v.z; wv[3] = (__bf16)v.w;
            *(bf16x4*)(&Y[0][r * STRIDE + lane * 4]) = wv;
        }
    } else {
#pragma unroll
        for (int s = 0; s < 2; ++s)
#pragma unroll
            for (int ks = 0; ks < 16; ++ks)
                wf[s][ks] = wp[(s << 10) + (ks << 6)];
        if (nt > 1) {
            const int rb1 = (slot + 32) * MT;
#pragma unroll
            for (int p = 0; p < 8; ++p)
                gcur[p] = idx_e[min(rb1 + w * 8 + p, ce - 1)];
        }
    }

    // ---- hoisted constants
    const float sa = sigmoid_f(shifta[0]);
    const float sb = sigmoid_f(shiftb[0]);
    const float k1 = 0.5f * (sb + sa);           // 0.5*(b-a), a=-sa, b=sb
    const float k2 = 0.5f * (sb - sa);           // 0.5*(a+b)
    const bool needy = (k2 != 0.0f);             // exactly 0 with given inputs
    float b1v[2], b2v[2], cc[2];
    b1v[0] = b1[(e << 8) | n0]; b1v[1] = b1[(e << 8) | n1];
    b2v[0] = b2[(e << 8) | n0]; b2v[1] = b2[(e << 8) | n1];
    cc[0]  = k1 * sigmoid_f(scales[n0]); cc[1] = k1 * sigmoid_f(scales[n1]);

    lds_barrier();

    // ---- region t: G1 computes tile t; G2 prefetches idx t+2, y-loads
    // tile t+1 (via gcur), computes tile t-1, write-late stages t+1.
    for (int t = 0; t <= nt; ++t) {
        if (isG1) {
            if (t < nt) {
                const __bf16* ap = &Y[t & 1][nl * STRIDE + kh * 8];
                f32x16 a0v = {}, a1v = {};
                __builtin_amdgcn_s_setprio(1);
#pragma unroll
                for (int ks = 0; ks < 16; ++ks) {
                    bf16x8 a = *(const bf16x8*)(ap + ks * 16);   // 1 read, 2 MFMA
                    a0v = __builtin_amdgcn_mfma_f32_32x32x16_bf16(a, wf[0][ks], a0v, 0, 0, 0);
                    a1v = __builtin_amdgcn_mfma_f32_32x32x16_bf16(a, wf[1][ks], a1v, 0, 0, 0);
                }
                __builtin_amdgcn_s_setprio(0);
                __bf16* hb = &H[t & 1][0];
#pragma unroll
                for (int r = 0; r < 16; ++r) {
                    const int row = (r & 3) + ((r >> 2) << 3) + (kh << 2);
                    hb[row * STRIDE + n0] = (__bf16)tanh_f(a0v[r] + b1v[0]);
                    hb[row * STRIDE + n1] = (__bf16)tanh_f(a1v[r] + b1v[1]);
                }
            }
        } else {
            // (1) index prefetch for tile t+2 (consumed next region)
            int gnew[8];
            if (t + 2 < nt) {
                const int rb = (slot + (t + 2) * 32) * MT;
#pragma unroll
                for (int p = 0; p < 8; ++p)
                    gnew[p] = idx_e[min(rb + w * 8 + p, ce - 1)];
            }
            // (2) y loads for tile t+1 (indices already in regs — no chain)
            const bool do_stage = (t + 1 < nt);
            float4 vs[8];
            if (do_stage) {
#pragma unroll
                for (int p = 0; p < 8; ++p)
                    vs[p] = *(const float4*)(y + (long)gcur[p] * DIM + lane * 4);
            }
            // (3) compute tile t-1
            if (t >= 1) {
                const __bf16* ap = &H[(t - 1) & 1][nl * STRIDE + kh * 8];
                f32x16 a0v = {}, a1v = {};
                __builtin_amdgcn_s_setprio(1);
#pragma unroll
                for (int ks = 0; ks < 16; ++ks) {
                    bf16x8 a = *(const bf16x8*)(ap + ks * 16);
                    a0v = __builtin_amdgcn_mfma_f32_32x32x16_bf16(a, wf[0][ks], a0v, 0, 0, 0);
                    a1v = __builtin_amdgcn_mfma_f32_32x32x16_bf16(a, wf[1][ks], a1v, 0, 0, 0);
                }
                __builtin_amdgcn_s_setprio(0);
                const int* rb = rowsb[(t - 1) & 3];
#pragma unroll
                for (int r = 0; r < 16; ++r) {
                    const int row = (r & 3) + ((r >> 2) << 3) + (kh << 2);
                    const int g = rb[row];
                    if (g >= 0) {
                        float r0 = cc[0] * (a0v[r] + b2v[0]);
                        float r1 = cc[1] * (a1v[r] + b2v[1]);
                        if (needy) {
                            r0 += k2 * y[(long)g * DIM + n0];
                            r1 += k2 * y[(long)g * DIM + n1];
                        }
                        out[(long)g * DIM + n0] = r0;
                        out[(long)g * DIM + n1] = r1;
                    }
                }
            }
            // (4) write-late stage of tile t+1; advance index ring
            if (do_stage) {
                const int kb = t + 1;
                const int rbs = (slot + kb * 32) * MT;
#pragma unroll
                for (int p = 0; p < 8; ++p) {
                    const int r = w * 8 + p;
                    if (lane == 0) rowsb[kb & 3][r] = (rbs + r < ce) ? gcur[p] : -1;
                    const float4 v = vs[p];
                    bf16x4 wv;
                    wv[0] = (__bf16)v.x; wv[1] = (__bf16)v.y; wv[2] = (__bf16)v.z; wv[3] = (__bf16)v.w;
                    *(bf16x4*)(&Y[kb & 1][r * STRIDE + lane * 4]) = wv;
                }
#pragma unroll
                for (int p = 0; p < 8; ++p) gcur[p] = gnew[p];
            }
        }
        lds_barrier();
    }
}

extern "C" void kernel_launch(void* const* d_in, const int* in_sizes, int n_in,
                              void* d_out, int out_size, void* d_ws, size_t ws_size,
                              hipStream_t stream) {
    const float* t      = (const float*)d_in[0];
    const float* y      = (const float*)d_in[1];
    const float* W1     = (const float*)d_in[2];
    const float* b1     = (const float*)d_in[3];
    const float* W2     = (const float*)d_in[4];
    const float* b2     = (const float*)d_in[5];
    const float* scales = (const float*)d_in[6];
    const float* shifta = (const float*)d_in[7];
    const float* shiftb = (const float*)d_in[8];
    float* out = (float*)d_out;

    char* ws = (char*)d_ws;
    int* cursor = (int*)ws;                               // [8]
    int* idxb   = (int*)(ws + 256);                       // [8][32768]
    bf16x8* W1p = (bf16x8*)(ws + 256 + NEXP * BATCH * 4); // packed 1MB
    bf16x8* W2p = W1p + 65536;

    hipMemsetAsync(cursor, 0, 32, stream);
    prep_kernel<<<384, 256, 0, stream>>>(W1, W2, t, W1p, W2p, cursor, idxb);
    // 256 expert-pinned blocks (32 per expert), 1 block/CU
    mlp_kernel<<<256, 512, 0, stream>>>(y, scales, shifta, shiftb, b1, b2,
                                        W1p, W2p, cursor, idxb, out);
}